// Round 1
// baseline (1453.661 us; speedup 1.0000x reference)
//
#include <hip/hip_runtime.h>
#include <hip/hip_bf16.h>

// Problem: RoPEAttention  B=2 S=2048 D=1024 H=16 HD=64, fp32 in/out.
// R1: all-fp32 correctness-first pipeline.
//   ws layout (floats): q[0,4M) k[4M,8M) v[8M,12M) pout[12M,28M) pml[28M,28.5M)
//   attn (combine output) aliases q region (q dead after flash_partial).

#define B_ 2
#define S_ 2048
#define D_ 1024
#define H_ 16
#define HD_ 64
#define M_ (B_*S_)
#define SPLIT_ 4
#define KCHUNK_ (S_/SPLIT_)   // 512

// ---------------- GEMM NT: C[m,n] = sum_k A[m,k] * W[n,k] ----------------
// A: [M_,D_] row-major. W: [D_,D_] row-major (output dim = rows). 128x128 tile, 8x8 micro.
// MODE 0: three weights/outputs (qkv), epilogue writes [B,H,S,HD]. MODE 1: plain [M,N] to C.
template<int MODE>
__global__ __launch_bounds__(256, 2)
void gemm_nt(const float* __restrict__ A,
             const float* __restrict__ Wq, const float* __restrict__ Wk, const float* __restrict__ Wv,
             float* __restrict__ Cq, float* __restrict__ Ck, float* __restrict__ Cv)
{
    __shared__ float As[16][132];
    __shared__ float Bs[16][132];
    const int tid = threadIdx.x;
    const int bm0 = blockIdx.x * 128;
    const int bn0 = blockIdx.y * 128;
    const float* W = Wq; float* C = Cq;
    if (MODE == 0) {
        if (blockIdx.z == 1)      { W = Wk; C = Ck; }
        else if (blockIdx.z == 2) { W = Wv; C = Cv; }
    }
    const int srow = tid >> 1;          // 0..127
    const int scol = (tid & 1) * 8;     // 0 or 8
    const int tx = tid & 15, ty = tid >> 4;
    float acc[8][8] = {};
    for (int k0 = 0; k0 < D_; k0 += 16) {
        float4 a0 = *(const float4*)(A + (size_t)(bm0 + srow) * D_ + k0 + scol);
        float4 a1 = *(const float4*)(A + (size_t)(bm0 + srow) * D_ + k0 + scol + 4);
        float4 b0 = *(const float4*)(W + (size_t)(bn0 + srow) * D_ + k0 + scol);
        float4 b1 = *(const float4*)(W + (size_t)(bn0 + srow) * D_ + k0 + scol + 4);
        __syncthreads();
        As[scol+0][srow] = a0.x; As[scol+1][srow] = a0.y; As[scol+2][srow] = a0.z; As[scol+3][srow] = a0.w;
        As[scol+4][srow] = a1.x; As[scol+5][srow] = a1.y; As[scol+6][srow] = a1.z; As[scol+7][srow] = a1.w;
        Bs[scol+0][srow] = b0.x; Bs[scol+1][srow] = b0.y; Bs[scol+2][srow] = b0.z; Bs[scol+3][srow] = b0.w;
        Bs[scol+4][srow] = b1.x; Bs[scol+5][srow] = b1.y; Bs[scol+6][srow] = b1.z; Bs[scol+7][srow] = b1.w;
        __syncthreads();
        #pragma unroll
        for (int k = 0; k < 16; ++k) {
            float av[8], bv[8];
            *(float4*)&av[0] = *(const float4*)&As[k][ty*8];
            *(float4*)&av[4] = *(const float4*)&As[k][ty*8+4];
            *(float4*)&bv[0] = *(const float4*)&Bs[k][tx*8];
            *(float4*)&bv[4] = *(const float4*)&Bs[k][tx*8+4];
            #pragma unroll
            for (int i = 0; i < 8; ++i)
                #pragma unroll
                for (int j = 0; j < 8; ++j)
                    acc[i][j] += av[i] * bv[j];
        }
    }
    #pragma unroll
    for (int i = 0; i < 8; ++i) {
        const int m = bm0 + ty*8 + i;
        const int b = m >> 11, s = m & (S_-1);
        #pragma unroll
        for (int j = 0; j < 8; ++j) {
            const int n = bn0 + tx*8 + j;
            if (MODE == 0) {
                const int h = n >> 6, hd = n & 63;
                C[(((size_t)b*H_ + h)*S_ + s)*HD_ + hd] = acc[i][j];
            } else {
                C[(size_t)m*D_ + n] = acc[i][j];
            }
        }
    }
}

// ---------------- RMSNorm + RoPE, in place, one wave per (b,h,s) row ----------------
__global__ __launch_bounds__(256)
void rmsnorm_rope(float* __restrict__ q, float* __restrict__ k,
                  const float* __restrict__ q_scale, const float* __restrict__ k_scale,
                  const float* __restrict__ rope_cos, const float* __restrict__ rope_sin)
{
    const int lane = threadIdx.x & 63;
    const int wid  = threadIdx.x >> 6;
    const int row  = blockIdx.x * 4 + wid;            // 0 .. B*H*S-1
    float* t = (blockIdx.y == 0) ? q : k;
    const float* sc = (blockIdx.y == 0) ? q_scale : k_scale;
    const int s = row & (S_-1);
    float v = t[(size_t)row * HD_ + lane];
    float ssum = v * v;
    #pragma unroll
    for (int m = 32; m >= 1; m >>= 1) ssum += __shfl_xor(ssum, m, 64);
    float r = rsqrtf(ssum * (1.0f/64.0f) + 1e-6f);
    float nv = v * r * sc[lane];
    const int p = lane >> 1;
    float c  = rope_cos[s*32 + p];
    float sn = rope_sin[s*32 + p];
    float partner = __shfl_xor(nv, 1, 64);
    float outv = (lane & 1) ? (partner * sn + nv * c) : (nv * c - partner * sn);
    t[(size_t)row * HD_ + lane] = outv;
}

// ---------------- Flash attention partial (split-K), thread-per-query ----------------
__global__ __launch_bounds__(256, 2)
void flash_partial(const float* __restrict__ qws, const float* __restrict__ kws,
                   const float* __restrict__ vws, float* __restrict__ pout,
                   float* __restrict__ pml)
{
    __shared__ float Ks[64][64];
    __shared__ float Vs[64][64];
    const int tid  = threadIdx.x;
    const int bh   = blockIdx.y;                       // b*H + h
    const int qidx = blockIdx.x * 256 + tid;           // 0..S-1
    const int sp   = blockIdx.z;
    const size_t baseQ = ((size_t)bh * S_ + qidx) * HD_;
    const size_t baseK = ((size_t)bh * S_ + (size_t)sp * KCHUNK_) * HD_;
    const float qscale = 0.125f * 1.44269504088896340736f;   // 1/sqrt(HD) * log2(e)
    float qr[64];
    #pragma unroll
    for (int d4 = 0; d4 < 16; ++d4) {
        float4 t = *(const float4*)(qws + baseQ + d4*4);
        qr[d4*4+0] = t.x*qscale; qr[d4*4+1] = t.y*qscale;
        qr[d4*4+2] = t.z*qscale; qr[d4*4+3] = t.w*qscale;
    }
    float m = -__builtin_inff(), l = 0.0f;
    float o[64];
    #pragma unroll
    for (int d = 0; d < 64; ++d) o[d] = 0.0f;

    const int lr = tid >> 2;             // 0..63
    const int lc = (tid & 3) * 16;       // 0,16,32,48
    for (int kt = 0; kt < KCHUNK_; kt += 64) {
        __syncthreads();
        #pragma unroll
        for (int u = 0; u < 4; ++u) {
            *(float4*)&Ks[lr][lc + u*4] = *(const float4*)(kws + baseK + (size_t)(kt + lr)*HD_ + lc + u*4);
            *(float4*)&Vs[lr][lc + u*4] = *(const float4*)(vws + baseK + (size_t)(kt + lr)*HD_ + lc + u*4);
        }
        __syncthreads();
        #pragma unroll
        for (int j0 = 0; j0 < 64; j0 += 8) {
            float sc8[8];
            #pragma unroll
            for (int jj = 0; jj < 8; ++jj) {
                const float4* kr = (const float4*)&Ks[j0+jj][0];
                float s0 = 0.f, s1 = 0.f, s2 = 0.f, s3 = 0.f;
                #pragma unroll
                for (int dq = 0; dq < 16; ++dq) {
                    float4 kk = kr[dq];
                    s0 += qr[dq*4+0]*kk.x; s1 += qr[dq*4+1]*kk.y;
                    s2 += qr[dq*4+2]*kk.z; s3 += qr[dq*4+3]*kk.w;
                }
                sc8[jj] = (s0+s1)+(s2+s3);
            }
            float cmax = sc8[0];
            #pragma unroll
            for (int jj = 1; jj < 8; ++jj) cmax = fmaxf(cmax, sc8[jj]);
            float mnew = fmaxf(m, cmax);
            float alpha = __builtin_amdgcn_exp2f(m - mnew);   // m=-inf first time -> 0
            l *= alpha;
            #pragma unroll
            for (int d = 0; d < 64; ++d) o[d] *= alpha;
            #pragma unroll
            for (int jj = 0; jj < 8; ++jj) {
                float p = __builtin_amdgcn_exp2f(sc8[jj] - mnew);
                l += p;
                const float4* vr = (const float4*)&Vs[j0+jj][0];
                #pragma unroll
                for (int dq = 0; dq < 16; ++dq) {
                    float4 vv = vr[dq];
                    o[dq*4+0] += p*vv.x; o[dq*4+1] += p*vv.y;
                    o[dq*4+2] += p*vv.z; o[dq*4+3] += p*vv.w;
                }
            }
            m = mnew;
        }
    }
    const size_t prow = ((size_t)bh * S_ + qidx) * SPLIT_ + sp;
    #pragma unroll
    for (int d4 = 0; d4 < 16; ++d4) {
        float4 t; t.x = o[d4*4+0]; t.y = o[d4*4+1]; t.z = o[d4*4+2]; t.w = o[d4*4+3];
        *(float4*)(pout + prow*64 + d4*4) = t;
    }
    pml[prow*2+0] = m;
    pml[prow*2+1] = l;
}

// ---------------- Combine split-K partials -> attn [B,S,H,HD] ----------------
__global__ __launch_bounds__(256)
void flash_combine(const float* __restrict__ pout, const float* __restrict__ pml,
                   float* __restrict__ attn)
{
    const int idx = blockIdx.x * 256 + threadIdx.x;    // 0 .. B*H*S*HD-1
    const int d   = idx & 63;
    const int row = idx >> 6;                          // bh*S + q
    const int q   = row & (S_-1);
    const int bh  = row >> 11;
    const int b   = bh >> 4, h = bh & (H_-1);
    float mm[SPLIT_], ll[SPLIT_];
    float M = -__builtin_inff();
    #pragma unroll
    for (int i = 0; i < SPLIT_; ++i) {
        mm[i] = pml[((size_t)row*SPLIT_ + i)*2+0];
        ll[i] = pml[((size_t)row*SPLIT_ + i)*2+1];
        M = fmaxf(M, mm[i]);
    }
    float L = 0.f, val = 0.f;
    #pragma unroll
    for (int i = 0; i < SPLIT_; ++i) {
        float w = __builtin_amdgcn_exp2f(mm[i] - M);
        L   += ll[i] * w;
        val += pout[((size_t)row*SPLIT_ + i)*64 + d] * w;
    }
    attn[(((size_t)b*S_ + q)*H_ + h)*HD_ + d] = val / L;
}

extern "C" void kernel_launch(void* const* d_in, const int* in_sizes, int n_in,
                              void* d_out, int out_size, void* d_ws, size_t ws_size,
                              hipStream_t stream)
{
    (void)in_sizes; (void)n_in; (void)out_size; (void)ws_size;
    const float* x        = (const float*)d_in[0];
    const float* wq       = (const float*)d_in[1];
    const float* wk       = (const float*)d_in[2];
    const float* wv       = (const float*)d_in[3];
    const float* wo       = (const float*)d_in[4];
    const float* q_scale  = (const float*)d_in[5];
    const float* k_scale  = (const float*)d_in[6];
    const float* rope_cos = (const float*)d_in[7];
    const float* rope_sin = (const float*)d_in[8];
    float* out = (float*)d_out;
    float* ws  = (float*)d_ws;

    float* q_ws = ws;                        // 4M floats
    float* k_ws = ws + (1ull<<22);
    float* v_ws = ws + (2ull<<22);
    float* pout = ws + (3ull<<22);           // 16M floats
    float* pml  = ws + (7ull<<22);           // 512K floats
    float* attn = q_ws;                      // alias: q dead after flash_partial

    gemm_nt<0><<<dim3(M_/128, D_/128, 3), 256, 0, stream>>>(x, wq, wk, wv, q_ws, k_ws, v_ws);
    rmsnorm_rope<<<dim3(B_*H_*S_/4, 2), 256, 0, stream>>>(q_ws, k_ws, q_scale, k_scale, rope_cos, rope_sin);
    flash_partial<<<dim3(S_/256, B_*H_, SPLIT_), 256, 0, stream>>>(q_ws, k_ws, v_ws, pout, pml);
    flash_combine<<<dim3((B_*H_*S_*HD_)/256), 256, 0, stream>>>(pout, pml, attn);
    gemm_nt<1><<<dim3(M_/128, D_/128, 1), 256, 0, stream>>>(attn, wo, wo, wo, out, out, out);
}

// Round 2
// 704.078 us; speedup vs baseline: 2.0646x; 2.0646x over previous
//
#include <hip/hip_runtime.h>
#include <hip/hip_bf16.h>

// RoPEAttention B=2 S=2048 D=1024 H=16 HD=64, fp32 in/out.
// R2: bf16 MFMA flash attention (16x16x32), fp32 GEMMs unchanged.
// ws layout (float units):
//   qf [0,4M) kf [4M,8M) | qb(bf16) [8M,10M) kb [10M,12M) vb [12M,14M) | attn [14M,18M)

#define B_ 2
#define S_ 2048
#define D_ 1024
#define H_ 16
#define HD_ 64
#define M_ (B_*S_)

typedef __attribute__((ext_vector_type(8))) short short8;
typedef __attribute__((ext_vector_type(4))) float f32x4;

static __device__ inline short f2bf(float f) {
    __hip_bfloat16 h = __float2bfloat16(f);
    return *reinterpret_cast<short*>(&h);
}

// ---------------- GEMM NT: C[m,n] = sum_k A[m,k] * W[n,k] ----------------
// MODE 0: z=0 -> q fp32 [B,H,S,HD]; z=1 -> k fp32 [B,H,S,HD]; z=2 -> v bf16 [B,H,S,HD]
// MODE 1: plain fp32 [M,N]
template<int MODE>
__global__ __launch_bounds__(256, 2)
void gemm_nt(const float* __restrict__ A,
             const float* __restrict__ Wq, const float* __restrict__ Wk, const float* __restrict__ Wv,
             float* __restrict__ Cq, float* __restrict__ Ck, short* __restrict__ Vb)
{
    __shared__ float As[16][132];
    __shared__ float Bs[16][132];
    const int tid = threadIdx.x;
    const int bm0 = blockIdx.x * 128;
    const int bn0 = blockIdx.y * 128;
    const float* W = Wq;
    if (MODE == 0) {
        if (blockIdx.z == 1)      W = Wk;
        else if (blockIdx.z == 2) W = Wv;
    }
    const int srow = tid >> 1;
    const int scol = (tid & 1) * 8;
    const int tx = tid & 15, ty = tid >> 4;
    float acc[8][8] = {};
    for (int k0 = 0; k0 < D_; k0 += 16) {
        float4 a0 = *(const float4*)(A + (size_t)(bm0 + srow) * D_ + k0 + scol);
        float4 a1 = *(const float4*)(A + (size_t)(bm0 + srow) * D_ + k0 + scol + 4);
        float4 b0 = *(const float4*)(W + (size_t)(bn0 + srow) * D_ + k0 + scol);
        float4 b1 = *(const float4*)(W + (size_t)(bn0 + srow) * D_ + k0 + scol + 4);
        __syncthreads();
        As[scol+0][srow] = a0.x; As[scol+1][srow] = a0.y; As[scol+2][srow] = a0.z; As[scol+3][srow] = a0.w;
        As[scol+4][srow] = a1.x; As[scol+5][srow] = a1.y; As[scol+6][srow] = a1.z; As[scol+7][srow] = a1.w;
        Bs[scol+0][srow] = b0.x; Bs[scol+1][srow] = b0.y; Bs[scol+2][srow] = b0.z; Bs[scol+3][srow] = b0.w;
        Bs[scol+4][srow] = b1.x; Bs[scol+5][srow] = b1.y; Bs[scol+6][srow] = b1.z; Bs[scol+7][srow] = b1.w;
        __syncthreads();
        #pragma unroll
        for (int k = 0; k < 16; ++k) {
            float av[8], bv[8];
            *(float4*)&av[0] = *(const float4*)&As[k][ty*8];
            *(float4*)&av[4] = *(const float4*)&As[k][ty*8+4];
            *(float4*)&bv[0] = *(const float4*)&Bs[k][tx*8];
            *(float4*)&bv[4] = *(const float4*)&Bs[k][tx*8+4];
            #pragma unroll
            for (int i = 0; i < 8; ++i)
                #pragma unroll
                for (int j = 0; j < 8; ++j)
                    acc[i][j] += av[i] * bv[j];
        }
    }
    #pragma unroll
    for (int i = 0; i < 8; ++i) {
        const int m = bm0 + ty*8 + i;
        const int b = m >> 11, s = m & (S_-1);
        #pragma unroll
        for (int j = 0; j < 8; ++j) {
            const int n = bn0 + tx*8 + j;
            if (MODE == 0) {
                const int h = n >> 6, hd = n & 63;
                const size_t idx = (((size_t)b*H_ + h)*S_ + s)*HD_ + hd;
                if (blockIdx.z == 2)      Vb[idx] = f2bf(acc[i][j]);
                else if (blockIdx.z == 1) Ck[idx] = acc[i][j];
                else                      Cq[idx] = acc[i][j];
            } else {
                Cq[(size_t)m*D_ + n] = acc[i][j];
            }
        }
    }
}

// ---------------- RMSNorm + RoPE: fp32 in -> bf16 out ----------------
// q output gets 1/sqrt(HD)*log2(e) folded in (flash works in exp2 domain).
__global__ __launch_bounds__(256)
void rmsnorm_rope(const float* __restrict__ q, const float* __restrict__ k,
                  short* __restrict__ qb, short* __restrict__ kb,
                  const float* __restrict__ q_scale, const float* __restrict__ k_scale,
                  const float* __restrict__ rope_cos, const float* __restrict__ rope_sin)
{
    const int lane = threadIdx.x & 63;
    const int wid  = threadIdx.x >> 6;
    const int row  = blockIdx.x * 4 + wid;
    const bool isq = (blockIdx.y == 0);
    const float* t = isq ? q : k;
    short* ob      = isq ? qb : kb;
    const float* sc = isq ? q_scale : k_scale;
    const int s = row & (S_-1);
    float v = t[(size_t)row * HD_ + lane];
    float ssum = v * v;
    #pragma unroll
    for (int m = 32; m >= 1; m >>= 1) ssum += __shfl_xor(ssum, m, 64);
    float r = rsqrtf(ssum * (1.0f/64.0f) + 1e-6f);
    float nv = v * r * sc[lane];
    const int p = lane >> 1;
    float c  = rope_cos[s*32 + p];
    float sn = rope_sin[s*32 + p];
    float partner = __shfl_xor(nv, 1, 64);
    float outv = (lane & 1) ? (partner * sn + nv * c) : (nv * c - partner * sn);
    if (isq) outv *= 0.18033688011112042f;   // (1/8) * log2(e)
    ob[(size_t)row * HD_ + lane] = f2bf(outv);
}

// ---------------- MFMA flash attention ----------------
// grid (S/64, B*H), block 256 (4 waves). Wave w: 16 queries.
// K tile 64x64 bf16 swizzled; V^T tile 64x64 bf16 swizzled; P via per-wave LDS.
__global__ __launch_bounds__(256, 2)
void flash_mfma(const short* __restrict__ qb, const short* __restrict__ kb,
                const short* __restrict__ vb, float* __restrict__ attn)
{
    __shared__ __align__(16) short Ks[64*64];
    __shared__ __align__(16) short Vt[64*64];
    __shared__ __align__(16) short Pl[4][16*64];

    const int tid  = threadIdx.x;
    const int wv   = tid >> 6;
    const int lane = tid & 63;
    const int quad = lane >> 4;
    const int l16  = lane & 15;
    const int bh   = blockIdx.y;
    const int b    = bh >> 4, h = bh & (H_-1);
    const int q0   = blockIdx.x * 64 + wv * 16;
    const size_t hbase = (size_t)bh * S_ * HD_;

    // Q fragments (A layout): lane holds Q[q0 + l16][c*32 + quad*8 .. +7]
    short8 qfrag[2];
    #pragma unroll
    for (int c = 0; c < 2; ++c)
        qfrag[c] = *(const short8*)(qb + hbase + (size_t)(q0 + l16)*HD_ + c*32 + quad*8);

    float m_r[4], l_r[4];
    f32x4 Oacc[4];
    #pragma unroll
    for (int r = 0; r < 4; ++r) {
        m_r[r] = -__builtin_inff(); l_r[r] = 0.f;
        Oacc[r] = (f32x4){0.f,0.f,0.f,0.f};
    }

    for (int kt = 0; kt < S_; kt += 64) {
        __syncthreads();
        // stage K tile: Ks[key][dchunk ^ (key&7)] (16B-chunk swizzle)
        #pragma unroll
        for (int c = tid; c < 512; c += 256) {
            const int key = c >> 3, dch = c & 7;
            short8 t = *(const short8*)(kb + hbase + (size_t)(kt + key)*HD_ + dch*8);
            *(short8*)(Ks + key*64 + (((dch ^ (key & 7)) << 3))) = t;
        }
        // stage V^T tile: Vt[d][keychunk ^ (d&7)]
        #pragma unroll
        for (int c = tid; c < 512; c += 256) {
            const int key = c >> 3, dch = c & 7;
            short8 t = *(const short8*)(vb + hbase + (size_t)(kt + key)*HD_ + dch*8);
            #pragma unroll
            for (int j = 0; j < 8; ++j) {
                const int d = dch*8 + j;
                Vt[d*64 + (((key >> 3) ^ (d & 7)) << 3) + (key & 7)] = t[j];
            }
        }
        __syncthreads();

        // scores: S[q][key] for 4 key-subtiles of 16
        f32x4 S4[4];
        #pragma unroll
        for (int st = 0; st < 4; ++st) {
            f32x4 acc = (f32x4){0.f,0.f,0.f,0.f};
            #pragma unroll
            for (int c = 0; c < 2; ++c) {
                short8 bf = *(const short8*)(Ks + (st*16 + l16)*64 + (((c*4 + quad) ^ (l16 & 7)) << 3));
                acc = __builtin_amdgcn_mfma_f32_16x16x32_bf16(qfrag[c], bf, acc, 0, 0, 0);
            }
            S4[st] = acc;
        }

        // online softmax (scores already in log2 domain)
        float alpha[4];
        #pragma unroll
        for (int r = 0; r < 4; ++r) {
            float mx = fmaxf(fmaxf(S4[0][r], S4[1][r]), fmaxf(S4[2][r], S4[3][r]));
            #pragma unroll
            for (int msk = 1; msk <= 8; msk <<= 1) mx = fmaxf(mx, __shfl_xor(mx, msk, 64));
            const float mnew = fmaxf(m_r[r], mx);
            alpha[r] = __builtin_amdgcn_exp2f(m_r[r] - mnew);
            m_r[r] = mnew;
        }
        float lsum[4] = {0.f,0.f,0.f,0.f};
        #pragma unroll
        for (int st = 0; st < 4; ++st)
            #pragma unroll
            for (int r = 0; r < 4; ++r) {
                float p = __builtin_amdgcn_exp2f(S4[st][r] - m_r[r]);
                lsum[r] += p;
                S4[st][r] = p;
            }
        #pragma unroll
        for (int r = 0; r < 4; ++r) {
            #pragma unroll
            for (int msk = 1; msk <= 8; msk <<= 1) lsum[r] += __shfl_xor(lsum[r], msk, 64);
            l_r[r] = l_r[r] * alpha[r] + lsum[r];
        }
        #pragma unroll
        for (int st = 0; st < 4; ++st)
            #pragma unroll
            for (int r = 0; r < 4; ++r)
                Oacc[st][r] *= alpha[r];

        // P: C layout -> A layout via per-wave swizzled LDS
        #pragma unroll
        for (int st = 0; st < 4; ++st) {
            const int key = st*16 + l16;
            #pragma unroll
            for (int r = 0; r < 4; ++r) {
                const int qq = quad*4 + r;
                Pl[wv][qq*64 + (((key >> 3) ^ (qq & 7)) << 3) + (key & 7)] = f2bf(S4[st][r]);
            }
        }
        // PV: O[q][d] += P[q][keys] * V[keys][d]
        #pragma unroll
        for (int c = 0; c < 2; ++c) {
            short8 pf = *(const short8*)(&Pl[wv][l16*64 + (((c*4 + quad) ^ (l16 & 7)) << 3)]);
            #pragma unroll
            for (int st = 0; st < 4; ++st) {
                short8 vf = *(const short8*)(Vt + (st*16 + l16)*64 + (((c*4 + quad) ^ (l16 & 7)) << 3));
                Oacc[st] = __builtin_amdgcn_mfma_f32_16x16x32_bf16(pf, vf, Oacc[st], 0, 0, 0);
            }
        }
    }

    // epilogue: normalize and write attn [B,S,H,HD]
    float linv[4];
    #pragma unroll
    for (int r = 0; r < 4; ++r) linv[r] = 1.0f / l_r[r];
    #pragma unroll
    for (int st = 0; st < 4; ++st)
        #pragma unroll
        for (int r = 0; r < 4; ++r)
            attn[((size_t)(b*S_ + q0 + quad*4 + r) * H_ + h) * HD_ + st*16 + l16] = Oacc[st][r] * linv[r];
}

extern "C" void kernel_launch(void* const* d_in, const int* in_sizes, int n_in,
                              void* d_out, int out_size, void* d_ws, size_t ws_size,
                              hipStream_t stream)
{
    (void)in_sizes; (void)n_in; (void)out_size; (void)ws_size;
    const float* x        = (const float*)d_in[0];
    const float* wq       = (const float*)d_in[1];
    const float* wk       = (const float*)d_in[2];
    const float* wv       = (const float*)d_in[3];
    const float* wo       = (const float*)d_in[4];
    const float* q_scale  = (const float*)d_in[5];
    const float* k_scale  = (const float*)d_in[6];
    const float* rope_cos = (const float*)d_in[7];
    const float* rope_sin = (const float*)d_in[8];
    float* out = (float*)d_out;
    float* ws  = (float*)d_ws;

    float* qf   = ws;                          // 4M floats
    float* kf   = ws + (1ull<<22);             // 4M floats
    short* qb   = (short*)(ws + (2ull<<22));   // 4M bf16
    short* kb   = (short*)(ws + (2ull<<22) + (1ull<<21));
    short* vb   = (short*)(ws + (2ull<<22) + (2ull<<21));
    float* attn = ws + (2ull<<22) + (3ull<<21)/1;   // after bf16 region
    attn = (float*)((char*)ws + 14ull*4*1024*1024); // 14M floats offset

    gemm_nt<0><<<dim3(M_/128, D_/128, 3), 256, 0, stream>>>(x, wq, wk, wv, qf, kf, vb);
    rmsnorm_rope<<<dim3(B_*H_*S_/4, 2), 256, 0, stream>>>(qf, kf, qb, kb, q_scale, k_scale, rope_cos, rope_sin);
    flash_mfma<<<dim3(S_/64, B_*H_), 256, 0, stream>>>(qb, kb, vb, attn);
    gemm_nt<1><<<dim3(M_/128, D_/128, 1), 256, 0, stream>>>(attn, wo, wo, wo, out, out, (short*)out);
}

// Round 3
// 258.662 us; speedup vs baseline: 5.6199x; 2.7220x over previous
//
#include <hip/hip_runtime.h>
#include <hip/hip_bf16.h>

// RoPEAttention B=2 S=2048 D=1024 H=16 HD=64, fp32 in/out.
// R3: bf16 MFMA everywhere. convert -> qkv GEMM (N=3072, MFMA) -> rmsnorm+rope
//     -> flash (fixed-m softmax, pre-transposed V) -> out GEMM (MFMA).
// ws (float units): qf[0,4M) kf[4M,8M) xb[8M,10M) wqkvb[10M,11.5M) wob[11.5M,12M)
//                   qb[12M,14M) kb[14M,16M) vt[16M,18M) attnb[18M,20M)

#define B_ 2
#define S_ 2048
#define D_ 1024
#define H_ 16
#define HD_ 64
#define M_ (B_*S_)

typedef __attribute__((ext_vector_type(8))) short short8;
typedef __attribute__((ext_vector_type(4))) short short4v;
typedef __attribute__((ext_vector_type(4))) float f32x4;

static __device__ __forceinline__ short f2bf(float f) {
    __hip_bfloat16 h = __float2bfloat16(f);
    return *reinterpret_cast<short*>(&h);
}

typedef __attribute__((address_space(1))) const unsigned int gu32_t;
typedef __attribute__((address_space(3))) unsigned int lu32_t;
static __device__ __forceinline__ void gld16(const short* g, short* l) {
    __builtin_amdgcn_global_load_lds((gu32_t*)g, (lu32_t*)l, 16, 0, 0);
}

// ---------------- fp32 -> bf16 convert: x, wq|wk|wv (concat), wo ----------------
__global__ __launch_bounds__(256)
void convert_bf16(const float* __restrict__ x,
                  const float* __restrict__ wq, const float* __restrict__ wk,
                  const float* __restrict__ wv, const float* __restrict__ wo,
                  short* __restrict__ xb, short* __restrict__ wqkvb, short* __restrict__ wob)
{
    const size_t t4 = ((size_t)blockIdx.x * 256 + threadIdx.x) * 4;
    const float* src; short* dst; size_t off;
    if (t4 < 4194304)      { src = x;  dst = xb;    off = t4; }
    else if (t4 < 5242880) { src = wq; dst = wqkvb + (t4 - 4194304); off = t4 - 4194304; dst = wqkvb; }
    else if (t4 < 6291456) { src = wk; dst = wqkvb; off = t4 - 5242880; }
    else if (t4 < 7340032) { src = wv; dst = wqkvb; off = t4 - 6291456; }
    else                   { src = wo; dst = wob;   off = t4 - 7340032; }
    // dst element offset within concat target
    size_t doff;
    if (t4 < 4194304)      doff = t4;
    else if (t4 < 7340032) doff = t4 - 4194304;   // wqkvb: wq|wk|wv contiguous
    else                   doff = t4 - 7340032;
    float4 v = *(const float4*)(src + off);
    short4v s = { f2bf(v.x), f2bf(v.y), f2bf(v.z), f2bf(v.w) };
    *(short4v*)(dst + doff) = s;
}

// ---------------- bf16 MFMA GEMM NT: C[m,n] = sum_k A[m,k]*Bw[n,k], K=1024 ----------------
// 128x128 tile, BK=32, 4 waves (2x2), 4x4 16x16x32 frags per wave.
// EPI 0: qkv fused N=3072: n>>10==0 -> Cq fp32 [B,H,S,HD]; ==1 -> Ck fp32; ==2 -> Vt bf16 [B,H,HD,S]
// EPI 1: Cout fp32 [M,1024]
template<int EPI>
__global__ __launch_bounds__(256)
void gemm_bf16(const short* __restrict__ A, const short* __restrict__ Bw,
               float* __restrict__ Cq, float* __restrict__ Ck,
               short* __restrict__ Vt, float* __restrict__ Cout)
{
    __shared__ __align__(16) short As[128*32];
    __shared__ __align__(16) short Bs[128*32];
    const int tid = threadIdx.x;
    const int w = tid >> 6, lane = tid & 63, quad = lane >> 4, l16 = lane & 15;
    const int wr = w >> 1, wc = w & 1;
    const int bm0 = blockIdx.x * 128, bn0 = blockIdx.y * 128;

    // staging: chunk c = it*256 + tid; row = c>>2, kch = c&3; LDS linear (chunk c at short-offset c*8)
    const int srow = tid >> 2;
    const int skch = (tid & 3) * 8;
    const short* gA0 = A  + (size_t)(bm0 + srow) * 1024 + skch;
    const short* gA1 = A  + (size_t)(bm0 + 64 + srow) * 1024 + skch;
    const short* gB0 = Bw + (size_t)(bn0 + srow) * 1024 + skch;
    const short* gB1 = Bw + (size_t)(bn0 + 64 + srow) * 1024 + skch;
    short* lA0 = As + w*512;
    short* lA1 = As + 2048 + w*512;
    short* lB0 = Bs + w*512;
    short* lB1 = Bs + 2048 + w*512;

    f32x4 acc[4][4];
    #pragma unroll
    for (int i = 0; i < 4; ++i)
        #pragma unroll
        for (int j = 0; j < 4; ++j) acc[i][j] = (f32x4){0.f,0.f,0.f,0.f};

    for (int k0 = 0; k0 < 1024; k0 += 32) {
        __syncthreads();
        gld16(gA0 + k0, lA0);
        gld16(gA1 + k0, lA1);
        gld16(gB0 + k0, lB0);
        gld16(gB1 + k0, lB1);
        __syncthreads();
        short8 af[4], bfr[4];
        #pragma unroll
        for (int i = 0; i < 4; ++i)
            af[i] = *(const short8*)(As + (wr*64 + i*16 + l16)*32 + quad*8);
        #pragma unroll
        for (int j = 0; j < 4; ++j)
            bfr[j] = *(const short8*)(Bs + (wc*64 + j*16 + l16)*32 + quad*8);
        #pragma unroll
        for (int i = 0; i < 4; ++i)
            #pragma unroll
            for (int j = 0; j < 4; ++j)
                acc[i][j] = __builtin_amdgcn_mfma_f32_16x16x32_bf16(af[i], bfr[j], acc[i][j], 0, 0, 0);
    }

    #pragma unroll
    for (int i = 0; i < 4; ++i) {
        #pragma unroll
        for (int r = 0; r < 4; ++r) {
            const int m = bm0 + wr*64 + i*16 + quad*4 + r;
            #pragma unroll
            for (int j = 0; j < 4; ++j) {
                const int n = bn0 + wc*64 + j*16 + l16;
                const float v = acc[i][j][r];
                if (EPI == 0) {
                    const int which = n >> 10, nn = n & 1023;
                    const int h = nn >> 6, hd = nn & 63;
                    const int b = m >> 11, s = m & (S_-1);
                    if (which == 0)      Cq[(((size_t)b*H_ + h)*S_ + s)*HD_ + hd] = v;
                    else if (which == 1) Ck[(((size_t)b*H_ + h)*S_ + s)*HD_ + hd] = v;
                    else                 Vt[(((size_t)b*H_ + h)*HD_ + hd)*S_ + s] = f2bf(v);
                } else {
                    Cout[(size_t)m*1024 + n] = v;
                }
            }
        }
    }
}

// ---------------- RMSNorm + RoPE: fp32 in -> bf16 out (q gets 1/8*log2e folded) ----------------
__global__ __launch_bounds__(256)
void rmsnorm_rope(const float* __restrict__ q, const float* __restrict__ k,
                  short* __restrict__ qb, short* __restrict__ kb,
                  const float* __restrict__ q_scale, const float* __restrict__ k_scale,
                  const float* __restrict__ rope_cos, const float* __restrict__ rope_sin)
{
    const int lane = threadIdx.x & 63;
    const int wid  = threadIdx.x >> 6;
    const int row  = blockIdx.x * 4 + wid;
    const bool isq = (blockIdx.y == 0);
    const float* t = isq ? q : k;
    short* ob      = isq ? qb : kb;
    const float* sc = isq ? q_scale : k_scale;
    const int s = row & (S_-1);
    float v = t[(size_t)row * HD_ + lane];
    float ssum = v * v;
    #pragma unroll
    for (int m = 32; m >= 1; m >>= 1) ssum += __shfl_xor(ssum, m, 64);
    float r = rsqrtf(ssum * (1.0f/64.0f) + 1e-6f);
    float nv = v * r * sc[lane];
    const int p = lane >> 1;
    float c  = rope_cos[s*32 + p];
    float sn = rope_sin[s*32 + p];
    float partner = __shfl_xor(nv, 1, 64);
    float outv = (lane & 1) ? (partner * sn + nv * c) : (nv * c - partner * sn);
    if (isq) outv *= 0.18033688011112042f;   // (1/8) * log2(e)
    ob[(size_t)row * HD_ + lane] = f2bf(outv);
}

// ---------------- MFMA flash attention, fixed-m softmax ----------------
// grid (S/64, B*H), 256 thr (4 waves, 16 queries each). Scores in log2 domain, m==12 bound.
__global__ __launch_bounds__(256, 2)
void flash_mfma(const short* __restrict__ qb, const short* __restrict__ kb,
                const short* __restrict__ vt, short* __restrict__ attnb)
{
    __shared__ __align__(16) short Ks[64*64];
    __shared__ __align__(16) short Vs[64*64];
    __shared__ __align__(16) short Pl[4][16*64];

    const int tid  = threadIdx.x;
    const int wv   = tid >> 6;
    const int lane = tid & 63;
    const int quad = lane >> 4;
    const int l16  = lane & 15;
    const int bh   = blockIdx.y;
    const int b    = bh >> 4, h = bh & (H_-1);
    const int q0   = blockIdx.x * 64 + wv * 16;
    const size_t hbase = (size_t)bh * S_ * HD_;   // qb/kb [B,H,S,HD]
    const size_t vbase = (size_t)bh * HD_ * S_;   // vt    [B,H,HD,S]

    short8 qfrag[2];
    #pragma unroll
    for (int c = 0; c < 2; ++c)
        qfrag[c] = *(const short8*)(qb + hbase + (size_t)(q0 + l16)*HD_ + c*32 + quad*8);

    float l_r[4] = {0.f, 0.f, 0.f, 0.f};
    f32x4 Oacc[4];
    #pragma unroll
    for (int st = 0; st < 4; ++st) Oacc[st] = (f32x4){0.f,0.f,0.f,0.f};

    for (int kt = 0; kt < S_; kt += 64) {
        __syncthreads();
        // K tile [key][d], 16B-chunk XOR swizzle
        #pragma unroll
        for (int c = tid; c < 512; c += 256) {
            const int key = c >> 3, dch = c & 7;
            short8 t = *(const short8*)(kb + hbase + (size_t)(kt + key)*HD_ + dch*8);
            *(short8*)(Ks + key*64 + ((dch ^ (key & 7)) << 3)) = t;
        }
        // V^T tile [d][key] from pre-transposed vt, vectorized, XOR swizzle
        #pragma unroll
        for (int c = tid; c < 512; c += 256) {
            const int d = c >> 3, kch = c & 7;
            short8 t = *(const short8*)(vt + vbase + (size_t)d*S_ + kt + kch*8);
            *(short8*)(Vs + d*64 + ((kch ^ (d & 7)) << 3)) = t;
        }
        __syncthreads();

        // scores (log2 domain; scale folded into q)
        f32x4 S4[4];
        #pragma unroll
        for (int st = 0; st < 4; ++st) {
            f32x4 acc = (f32x4){0.f,0.f,0.f,0.f};
            #pragma unroll
            for (int c = 0; c < 2; ++c) {
                short8 bf = *(const short8*)(Ks + (st*16 + l16)*64 + (((c*4 + quad) ^ (l16 & 7)) << 3));
                acc = __builtin_amdgcn_mfma_f32_16x16x32_bf16(qfrag[c], bf, acc, 0, 0, 0);
            }
            S4[st] = acc;
        }

        // p = exp2(s - 12)  (|s| <= 11.6 structurally: rmsnormed q,k)
        #pragma unroll
        for (int st = 0; st < 4; ++st) {
            const int key = st*16 + l16;
            #pragma unroll
            for (int r = 0; r < 4; ++r) {
                const float p = __builtin_amdgcn_exp2f(S4[st][r] - 12.0f);
                l_r[r] += p;
                const int qq = quad*4 + r;
                Pl[wv][qq*64 + ((((key >> 3) ^ (qq & 7)) << 3)) + (key & 7)] = f2bf(p);
            }
        }
        // PV
        #pragma unroll
        for (int c = 0; c < 2; ++c) {
            short8 pf = *(const short8*)(&Pl[wv][l16*64 + (((c*4 + quad) ^ (l16 & 7)) << 3)]);
            #pragma unroll
            for (int st = 0; st < 4; ++st) {
                short8 vf = *(const short8*)(Vs + (st*16 + l16)*64 + (((c*4 + quad) ^ (l16 & 7)) << 3));
                Oacc[st] = __builtin_amdgcn_mfma_f32_16x16x32_bf16(pf, vf, Oacc[st], 0, 0, 0);
            }
        }
    }

    // final l reduction across l16 within quad, then write attn bf16 [B,S,H*HD]
    #pragma unroll
    for (int r = 0; r < 4; ++r) {
        #pragma unroll
        for (int msk = 1; msk <= 8; msk <<= 1) l_r[r] += __shfl_xor(l_r[r], msk, 64);
        l_r[r] = 1.0f / l_r[r];
    }
    #pragma unroll
    for (int st = 0; st < 4; ++st)
        #pragma unroll
        for (int r = 0; r < 4; ++r) {
            const int s = q0 + quad*4 + r;
            attnb[(((size_t)b*S_ + s)*H_ + h)*HD_ + st*16 + l16] = f2bf(Oacc[st][r] * l_r[r]);
        }
}

extern "C" void kernel_launch(void* const* d_in, const int* in_sizes, int n_in,
                              void* d_out, int out_size, void* d_ws, size_t ws_size,
                              hipStream_t stream)
{
    (void)in_sizes; (void)n_in; (void)out_size; (void)ws_size;
    const float* x        = (const float*)d_in[0];
    const float* wq       = (const float*)d_in[1];
    const float* wk       = (const float*)d_in[2];
    const float* wv       = (const float*)d_in[3];
    const float* wo       = (const float*)d_in[4];
    const float* q_scale  = (const float*)d_in[5];
    const float* k_scale  = (const float*)d_in[6];
    const float* rope_cos = (const float*)d_in[7];
    const float* rope_sin = (const float*)d_in[8];
    float* out = (float*)d_out;
    float* ws  = (float*)d_ws;

    float* qf    = ws;                                  // [0,4M)
    float* kf    = ws + (1ull<<22);                     // [4M,8M)
    short* xb    = (short*)(ws + (2ull<<22));           // [8M,10M)
    short* wqkvb = (short*)(ws + (2ull<<22) + 2097152); // [10M,11.5M)
    short* wob   = (short*)(ws + (2ull<<22) + 3670016); // [11.5M,12M)
    short* qb    = (short*)(ws + 12582912);             // [12M,14M)
    short* kb    = (short*)(ws + 14680064);             // [14M,16M)
    short* vt    = (short*)(ws + 16777216);             // [16M,18M)
    short* attnb = (short*)(ws + 18874368);             // [18M,20M)

    convert_bf16<<<dim3(8192), 256, 0, stream>>>(x, wq, wk, wv, wo, xb, wqkvb, wob);
    gemm_bf16<0><<<dim3(M_/128, 24), 256, 0, stream>>>(xb, wqkvb, qf, kf, vt, nullptr);
    rmsnorm_rope<<<dim3(B_*H_*S_/4, 2), 256, 0, stream>>>(qf, kf, qb, kb, q_scale, k_scale, rope_cos, rope_sin);
    flash_mfma<<<dim3(S_/64, B_*H_), 256, 0, stream>>>(qb, kb, vt, attnb);
    gemm_bf16<1><<<dim3(M_/128, 8), 256, 0, stream>>>(attnb, wob, nullptr, nullptr, nullptr, out);
}

// Round 4
// 235.587 us; speedup vs baseline: 6.1704x; 1.0979x over previous
//
#include <hip/hip_runtime.h>
#include <hip/hip_bf16.h>

// RoPEAttention B=2 S=2048 D=1024 H=16 HD=64, fp32 in/out.
// R4: flash rewrite: S^T trick (A=K,B=Q) -> P stays in registers as B-frag for
//     f16 16x16x16 PV MFMA (no LDS transpose); 32 q/wave, 128 q/block.
//     GEMM1 writes q/k bf16 (rmsnorm in-place), V f16 pre-transposed [B,H,HD,S].
// ws (shorts): qbh[0,4M) kbh[4M,8M) vt[8M,12M) attnb[12M,16M) xb[16M,20M)
//              wqkvb[20M,23M) wob[23M,24M)

#define B_ 2
#define S_ 2048
#define D_ 1024
#define H_ 16
#define HD_ 64
#define M_ (B_*S_)

typedef __attribute__((ext_vector_type(8))) short short8;
typedef __attribute__((ext_vector_type(4))) short short4v;
typedef __attribute__((ext_vector_type(4))) float f32x4;
typedef __attribute__((ext_vector_type(4))) _Float16 half4;

static __device__ __forceinline__ short f2bf(float f) {
    __hip_bfloat16 h = __float2bfloat16(f);
    return *reinterpret_cast<short*>(&h);
}
static __device__ __forceinline__ short f2h(float f) {
    _Float16 h = (_Float16)f;
    return *reinterpret_cast<short*>(&h);
}
static __device__ __forceinline__ float bf2f(short s) {
    unsigned u = ((unsigned)(unsigned short)s) << 16;
    float f; __builtin_memcpy(&f, &u, 4); return f;
}

typedef __attribute__((address_space(1))) const unsigned int gu32_t;
typedef __attribute__((address_space(3))) unsigned int lu32_t;
static __device__ __forceinline__ void gld16(const short* g, short* l) {
    __builtin_amdgcn_global_load_lds((gu32_t*)g, (lu32_t*)l, 16, 0, 0);
}

// ---------------- fp32 -> bf16 convert: x, wq|wk|wv (concat), wo ----------------
__global__ __launch_bounds__(256)
void convert_bf16(const float* __restrict__ x,
                  const float* __restrict__ wq, const float* __restrict__ wk,
                  const float* __restrict__ wv, const float* __restrict__ wo,
                  short* __restrict__ xb, short* __restrict__ wqkvb, short* __restrict__ wob)
{
    const size_t t4 = ((size_t)blockIdx.x * 256 + threadIdx.x) * 4;
    const float* src; short* dst; size_t off, doff;
    if (t4 < 4194304)      { src = x;  dst = xb;    off = t4;           doff = t4; }
    else if (t4 < 5242880) { src = wq; dst = wqkvb; off = t4 - 4194304; doff = t4 - 4194304; }
    else if (t4 < 6291456) { src = wk; dst = wqkvb; off = t4 - 5242880; doff = t4 - 4194304; }
    else if (t4 < 7340032) { src = wv; dst = wqkvb; off = t4 - 6291456; doff = t4 - 4194304; }
    else                   { src = wo; dst = wob;   off = t4 - 7340032; doff = t4 - 7340032; }
    float4 v = *(const float4*)(src + off);
    short4v s = { f2bf(v.x), f2bf(v.y), f2bf(v.z), f2bf(v.w) };
    *(short4v*)(dst + doff) = s;
}

// ---------------- bf16 MFMA GEMM NT: C[m,n] = sum_k A[m,k]*Bw[n,k], K=1024 ----------------
// EPI 0 (N=3072 fused): n>>10==0 -> Qb bf16 [B,H,S,HD]; ==1 -> Kb bf16; ==2 -> Vt f16 [B,H,HD,S]
// EPI 1: Cout fp32 [M,1024]
template<int EPI>
__global__ __launch_bounds__(256)
void gemm_bf16(const short* __restrict__ A, const short* __restrict__ Bw,
               short* __restrict__ Qb, short* __restrict__ Kb,
               short* __restrict__ Vt, float* __restrict__ Cout)
{
    __shared__ __align__(16) short As[128*32];
    __shared__ __align__(16) short Bs[128*32];
    const int tid = threadIdx.x;
    const int w = tid >> 6, lane = tid & 63, quad = lane >> 4, l16 = lane & 15;
    const int wr = w >> 1, wc = w & 1;
    const int bm0 = blockIdx.x * 128, bn0 = blockIdx.y * 128;

    const int srow = tid >> 2;
    const int skch = (tid & 3) * 8;
    const short* gA0 = A  + (size_t)(bm0 + srow) * 1024 + skch;
    const short* gA1 = A  + (size_t)(bm0 + 64 + srow) * 1024 + skch;
    const short* gB0 = Bw + (size_t)(bn0 + srow) * 1024 + skch;
    const short* gB1 = Bw + (size_t)(bn0 + 64 + srow) * 1024 + skch;
    short* lA0 = As + w*512;
    short* lA1 = As + 2048 + w*512;
    short* lB0 = Bs + w*512;
    short* lB1 = Bs + 2048 + w*512;

    f32x4 acc[4][4];
    #pragma unroll
    for (int i = 0; i < 4; ++i)
        #pragma unroll
        for (int j = 0; j < 4; ++j) acc[i][j] = (f32x4){0.f,0.f,0.f,0.f};

    for (int k0 = 0; k0 < 1024; k0 += 32) {
        __syncthreads();
        gld16(gA0 + k0, lA0);
        gld16(gA1 + k0, lA1);
        gld16(gB0 + k0, lB0);
        gld16(gB1 + k0, lB1);
        __syncthreads();
        short8 af[4], bfr[4];
        #pragma unroll
        for (int i = 0; i < 4; ++i)
            af[i] = *(const short8*)(As + (wr*64 + i*16 + l16)*32 + quad*8);
        #pragma unroll
        for (int j = 0; j < 4; ++j)
            bfr[j] = *(const short8*)(Bs + (wc*64 + j*16 + l16)*32 + quad*8);
        #pragma unroll
        for (int i = 0; i < 4; ++i)
            #pragma unroll
            for (int j = 0; j < 4; ++j)
                acc[i][j] = __builtin_amdgcn_mfma_f32_16x16x32_bf16(af[i], bfr[j], acc[i][j], 0, 0, 0);
    }

    #pragma unroll
    for (int i = 0; i < 4; ++i) {
        #pragma unroll
        for (int r = 0; r < 4; ++r) {
            const int m = bm0 + wr*64 + i*16 + quad*4 + r;
            #pragma unroll
            for (int j = 0; j < 4; ++j) {
                const int n = bn0 + wc*64 + j*16 + l16;
                const float v = acc[i][j][r];
                if (EPI == 0) {
                    const int which = n >> 10, nn = n & 1023;
                    const int h = nn >> 6, hd = nn & 63;
                    const int b = m >> 11, s = m & (S_-1);
                    if (which == 0)      Qb[(((size_t)b*H_ + h)*S_ + s)*HD_ + hd] = f2bf(v);
                    else if (which == 1) Kb[(((size_t)b*H_ + h)*S_ + s)*HD_ + hd] = f2bf(v);
                    else                 Vt[(((size_t)b*H_ + h)*HD_ + hd)*S_ + s] = f2h(v);
                } else {
                    Cout[(size_t)m*1024 + n] = v;
                }
            }
        }
    }
}

// ---------------- RMSNorm + RoPE, in place on bf16 (q gets 1/8*log2e folded) ----------------
__global__ __launch_bounds__(256)
void rmsnorm_rope(short* __restrict__ qbh, short* __restrict__ kbh,
                  const float* __restrict__ q_scale, const float* __restrict__ k_scale,
                  const float* __restrict__ rope_cos, const float* __restrict__ rope_sin)
{
    const int lane = threadIdx.x & 63;
    const int wid  = threadIdx.x >> 6;
    const int row  = blockIdx.x * 4 + wid;
    const bool isq = (blockIdx.y == 0);
    short* t = isq ? qbh : kbh;
    const float* sc = isq ? q_scale : k_scale;
    const int s = row & (S_-1);
    float v = bf2f(t[(size_t)row * HD_ + lane]);
    float ssum = v * v;
    #pragma unroll
    for (int m = 32; m >= 1; m >>= 1) ssum += __shfl_xor(ssum, m, 64);
    float r = rsqrtf(ssum * (1.0f/64.0f) + 1e-6f);
    float nv = v * r * sc[lane];
    const int p = lane >> 1;
    float c  = rope_cos[s*32 + p];
    float sn = rope_sin[s*32 + p];
    float partner = __shfl_xor(nv, 1, 64);
    float outv = (lane & 1) ? (partner * sn + nv * c) : (nv * c - partner * sn);
    if (isq) outv *= 0.18033688011112042f;   // (1/8) * log2(e)
    t[(size_t)row * HD_ + lane] = f2bf(outv);
}

// ---------------- MFMA flash attention, S^T + register-P path ----------------
// grid (S/128, B*H), 256 thr (4 waves x 32 queries). Fixed-m softmax (m=12, log2 domain).
// S^T[key][q] = mfma(A=K, B=Q): lane holds q=l16, keys=st*16+quad*4+r  ==
// exactly the B-operand layout of mfma_f32_16x16x16_f16 -> PV with A=V^T, no LDS.
__global__ __launch_bounds__(256, 2)
void flash_mfma(const short* __restrict__ qb, const short* __restrict__ kb,
                const short* __restrict__ vt, short* __restrict__ attnb)
{
    __shared__ __align__(16) short Ks[64*64];
    __shared__ __align__(16) short Vs[64*64];   // f16 bits, [d][key] swizzled

    const int tid  = threadIdx.x;
    const int wv   = tid >> 6;
    const int lane = tid & 63;
    const int quad = lane >> 4;
    const int l16  = lane & 15;
    const int bh   = blockIdx.y;
    const int b    = bh >> 4, h = bh & (H_-1);
    const int q0   = blockIdx.x * 128 + wv * 32;
    const size_t hbase = (size_t)bh * S_ * HD_;
    const size_t vbase = (size_t)bh * HD_ * S_;

    // Q fragments (B-operand layout): lane q=l16, d=c*32+quad*8..+7
    short8 qfrag[2][2];
    #pragma unroll
    for (int qf = 0; qf < 2; ++qf)
        #pragma unroll
        for (int c = 0; c < 2; ++c)
            qfrag[qf][c] = *(const short8*)(qb + hbase + (size_t)(q0 + qf*16 + l16)*HD_ + c*32 + quad*8);

    f32x4 Oacc[2][4];
    #pragma unroll
    for (int qf = 0; qf < 2; ++qf)
        #pragma unroll
        for (int dt = 0; dt < 4; ++dt) Oacc[qf][dt] = (f32x4){0.f,0.f,0.f,0.f};
    float l_lane[2] = {0.f, 0.f};

    #pragma unroll 1
    for (int kt = 0; kt < S_; kt += 64) {
        __syncthreads();
        // K tile [key][d], 16B-chunk XOR swizzle
        #pragma unroll
        for (int c = tid; c < 512; c += 256) {
            const int key = c >> 3, dch = c & 7;
            *(short8*)(Ks + key*64 + ((dch ^ (key & 7)) << 3)) =
                *(const short8*)(kb + hbase + (size_t)(kt + key)*HD_ + dch*8);
        }
        // V^T tile [d][key] (f16), 16B-chunk XOR swizzle
        #pragma unroll
        for (int c = tid; c < 512; c += 256) {
            const int d = c >> 3, kch = c & 7;
            *(short8*)(Vs + d*64 + ((kch ^ (d & 7)) << 3)) =
                *(const short8*)(vt + vbase + (size_t)d*S_ + kt + kch*8);
        }
        __syncthreads();

        #pragma unroll
        for (int st = 0; st < 4; ++st) {
            // K fragments (A-operand): lane key=st*16+l16, d chunks (c*4+quad)
            short8 kf0 = *(const short8*)(Ks + (st*16 + l16)*64 + (((quad    ) ^ (l16 & 7)) << 3));
            short8 kf1 = *(const short8*)(Ks + (st*16 + l16)*64 + (((4 + quad) ^ (l16 & 7)) << 3));
            #pragma unroll
            for (int qf = 0; qf < 2; ++qf) {
                f32x4 acc = (f32x4){0.f,0.f,0.f,0.f};
                acc = __builtin_amdgcn_mfma_f32_16x16x32_bf16(kf0, qfrag[qf][0], acc, 0, 0, 0);
                acc = __builtin_amdgcn_mfma_f32_16x16x32_bf16(kf1, qfrag[qf][1], acc, 0, 0, 0);
                // p = exp2(s - 12); accumulate l; pack P^T frag (f16) = B-operand for K=16 PV
                half4 pb;
                #pragma unroll
                for (int r = 0; r < 4; ++r) {
                    float p = __builtin_amdgcn_exp2f(acc[r] - 12.0f);
                    l_lane[qf] += p;
                    pb[r] = (_Float16)p;
                }
                // PV: O^T[d][q] += V^T[d][keys16] * P^T
                const int ch16 = st*2 + (quad >> 1);
                const int sw   = ((ch16 ^ (l16 & 7)) << 3) + (quad & 1)*4;
                #pragma unroll
                for (int dt = 0; dt < 4; ++dt) {
                    half4 va = *(const half4*)(Vs + (dt*16 + l16)*64 + sw);
                    Oacc[qf][dt] = __builtin_amdgcn_mfma_f32_16x16x16f16(va, pb, Oacc[qf][dt], 0, 0, 0);
                }
            }
        }
    }

    // l: reduce across quads (lane's q = l16, partials spread over quads)
    #pragma unroll
    for (int qf = 0; qf < 2; ++qf) {
        l_lane[qf] += __shfl_xor(l_lane[qf], 16, 64);
        l_lane[qf] += __shfl_xor(l_lane[qf], 32, 64);
        l_lane[qf] = 1.0f / l_lane[qf];
    }
    // write attn bf16 [B,S,H*HD]: lane q=l16, d = dt*16 + quad*4 + r
    #pragma unroll
    for (int qf = 0; qf < 2; ++qf) {
        const int s = q0 + qf*16 + l16;
        #pragma unroll
        for (int dt = 0; dt < 4; ++dt) {
            short4v o;
            #pragma unroll
            for (int r = 0; r < 4; ++r) o[r] = f2bf(Oacc[qf][dt][r] * l_lane[qf]);
            *(short4v*)(attnb + (((size_t)b*S_ + s)*H_ + h)*HD_ + dt*16 + quad*4) = o;
        }
    }
}

extern "C" void kernel_launch(void* const* d_in, const int* in_sizes, int n_in,
                              void* d_out, int out_size, void* d_ws, size_t ws_size,
                              hipStream_t stream)
{
    (void)in_sizes; (void)n_in; (void)out_size; (void)ws_size;
    const float* x        = (const float*)d_in[0];
    const float* wq       = (const float*)d_in[1];
    const float* wk       = (const float*)d_in[2];
    const float* wv       = (const float*)d_in[3];
    const float* wo       = (const float*)d_in[4];
    const float* q_scale  = (const float*)d_in[5];
    const float* k_scale  = (const float*)d_in[6];
    const float* rope_cos = (const float*)d_in[7];
    const float* rope_sin = (const float*)d_in[8];
    float* out = (float*)d_out;
    short* ws  = (short*)d_ws;

    short* qbh   = ws;                 // 4M shorts
    short* kbh   = ws + 4194304;
    short* vt    = ws + 8388608;
    short* attnb = ws + 12582912;
    short* xb    = ws + 16777216;
    short* wqkvb = ws + 20971520;      // 3M shorts
    short* wob   = ws + 24117248;      // 1M shorts

    convert_bf16<<<dim3(8192), 256, 0, stream>>>(x, wq, wk, wv, wo, xb, wqkvb, wob);
    gemm_bf16<0><<<dim3(M_/128, 24), 256, 0, stream>>>(xb, wqkvb, qbh, kbh, vt, nullptr);
    rmsnorm_rope<<<dim3(B_*H_*S_/4, 2), 256, 0, stream>>>(qbh, kbh, q_scale, k_scale, rope_cos, rope_sin);
    flash_mfma<<<dim3(S_/128, B_*H_), 256, 0, stream>>>(qbh, kbh, vt, attnb);
    gemm_bf16<1><<<dim3(M_/128, 8), 256, 0, stream>>>(attnb, wob, nullptr, nullptr, nullptr, out);
}

// Round 5
// 225.706 us; speedup vs baseline: 6.4405x; 1.0438x over previous
//
#include <hip/hip_runtime.h>
#include <hip/hip_bf16.h>

// RoPEAttention B=2 S=2048 D=1024 H=16 HD=64, fp32 in/out.
// R5: flash split-K=2 (fixed-m partials sum directly) + global->reg prefetch;
//     f16 partial O + combine kernel; out-proj GEMM retiled 64x128 (2 blk/CU).
// ws (shorts): qbh[0,4M) kbh[4M,8M) vt[8M,12M) attnb[12M,16M) xb[16M,20M)
//              wqkvb[20M,23M) wob[23M,24M) po[24M,32M) pl(fp32)[32M shorts...)

#define B_ 2
#define S_ 2048
#define D_ 1024
#define H_ 16
#define HD_ 64
#define M_ (B_*S_)

typedef __attribute__((ext_vector_type(8))) short short8;
typedef __attribute__((ext_vector_type(4))) short short4v;
typedef __attribute__((ext_vector_type(4))) float f32x4;
typedef __attribute__((ext_vector_type(4))) _Float16 half4;

static __device__ __forceinline__ short f2bf(float f) {
    __hip_bfloat16 h = __float2bfloat16(f);
    return *reinterpret_cast<short*>(&h);
}
static __device__ __forceinline__ short f2h(float f) {
    _Float16 h = (_Float16)f;
    return *reinterpret_cast<short*>(&h);
}
static __device__ __forceinline__ float h2f(short s) {
    _Float16 h; __builtin_memcpy(&h, &s, 2); return (float)h;
}
static __device__ __forceinline__ float bf2f(short s) {
    unsigned u = ((unsigned)(unsigned short)s) << 16;
    float f; __builtin_memcpy(&f, &u, 4); return f;
}

typedef __attribute__((address_space(1))) const unsigned int gu32_t;
typedef __attribute__((address_space(3))) unsigned int lu32_t;
static __device__ __forceinline__ void gld16(const short* g, short* l) {
    __builtin_amdgcn_global_load_lds((gu32_t*)g, (lu32_t*)l, 16, 0, 0);
}

// ---------------- fp32 -> bf16 convert: x, wq|wk|wv (concat), wo ----------------
__global__ __launch_bounds__(256)
void convert_bf16(const float* __restrict__ x,
                  const float* __restrict__ wq, const float* __restrict__ wk,
                  const float* __restrict__ wv, const float* __restrict__ wo,
                  short* __restrict__ xb, short* __restrict__ wqkvb, short* __restrict__ wob)
{
    const size_t t4 = ((size_t)blockIdx.x * 256 + threadIdx.x) * 4;
    const float* src; short* dst; size_t off, doff;
    if (t4 < 4194304)      { src = x;  dst = xb;    off = t4;           doff = t4; }
    else if (t4 < 5242880) { src = wq; dst = wqkvb; off = t4 - 4194304; doff = t4 - 4194304; }
    else if (t4 < 6291456) { src = wk; dst = wqkvb; off = t4 - 5242880; doff = t4 - 4194304; }
    else if (t4 < 7340032) { src = wv; dst = wqkvb; off = t4 - 6291456; doff = t4 - 4194304; }
    else                   { src = wo; dst = wob;   off = t4 - 7340032; doff = t4 - 7340032; }
    float4 v = *(const float4*)(src + off);
    short4v s = { f2bf(v.x), f2bf(v.y), f2bf(v.z), f2bf(v.w) };
    *(short4v*)(dst + doff) = s;
}

// ---------------- bf16 MFMA GEMM NT 128x128 (qkv fused, N=3072) ----------------
// n>>10==0 -> Qb bf16 [B,H,S,HD]; ==1 -> Kb bf16; ==2 -> Vt f16 [B,H,HD,S]
__global__ __launch_bounds__(256)
void gemm_qkv(const short* __restrict__ A, const short* __restrict__ Bw,
              short* __restrict__ Qb, short* __restrict__ Kb, short* __restrict__ Vt)
{
    __shared__ __align__(16) short As[128*32];
    __shared__ __align__(16) short Bs[128*32];
    const int tid = threadIdx.x;
    const int w = tid >> 6, lane = tid & 63, quad = lane >> 4, l16 = lane & 15;
    const int wr = w >> 1, wc = w & 1;
    const int bm0 = blockIdx.x * 128, bn0 = blockIdx.y * 128;

    const int srow = tid >> 2;
    const int skch = (tid & 3) * 8;
    const short* gA0 = A  + (size_t)(bm0 + srow) * 1024 + skch;
    const short* gA1 = A  + (size_t)(bm0 + 64 + srow) * 1024 + skch;
    const short* gB0 = Bw + (size_t)(bn0 + srow) * 1024 + skch;
    const short* gB1 = Bw + (size_t)(bn0 + 64 + srow) * 1024 + skch;
    short* lA0 = As + w*512;
    short* lA1 = As + 2048 + w*512;
    short* lB0 = Bs + w*512;
    short* lB1 = Bs + 2048 + w*512;

    f32x4 acc[4][4];
    #pragma unroll
    for (int i = 0; i < 4; ++i)
        #pragma unroll
        for (int j = 0; j < 4; ++j) acc[i][j] = (f32x4){0.f,0.f,0.f,0.f};

    for (int k0 = 0; k0 < 1024; k0 += 32) {
        __syncthreads();
        gld16(gA0 + k0, lA0);
        gld16(gA1 + k0, lA1);
        gld16(gB0 + k0, lB0);
        gld16(gB1 + k0, lB1);
        __syncthreads();
        short8 af[4], bfr[4];
        #pragma unroll
        for (int i = 0; i < 4; ++i)
            af[i] = *(const short8*)(As + (wr*64 + i*16 + l16)*32 + quad*8);
        #pragma unroll
        for (int j = 0; j < 4; ++j)
            bfr[j] = *(const short8*)(Bs + (wc*64 + j*16 + l16)*32 + quad*8);
        #pragma unroll
        for (int i = 0; i < 4; ++i)
            #pragma unroll
            for (int j = 0; j < 4; ++j)
                acc[i][j] = __builtin_amdgcn_mfma_f32_16x16x32_bf16(af[i], bfr[j], acc[i][j], 0, 0, 0);
    }

    #pragma unroll
    for (int i = 0; i < 4; ++i) {
        #pragma unroll
        for (int r = 0; r < 4; ++r) {
            const int m = bm0 + wr*64 + i*16 + quad*4 + r;
            #pragma unroll
            for (int j = 0; j < 4; ++j) {
                const int n = bn0 + wc*64 + j*16 + l16;
                const float v = acc[i][j][r];
                const int which = n >> 10, nn = n & 1023;
                const int h = nn >> 6, hd = nn & 63;
                const int b = m >> 11, s = m & (S_-1);
                if (which == 0)      Qb[(((size_t)b*H_ + h)*S_ + s)*HD_ + hd] = f2bf(v);
                else if (which == 1) Kb[(((size_t)b*H_ + h)*S_ + s)*HD_ + hd] = f2bf(v);
                else                 Vt[(((size_t)b*H_ + h)*HD_ + hd)*S_ + s] = f2h(v);
            }
        }
    }
}

// ---------------- out-proj GEMM, 64x128 tile (2 blk/CU) ----------------
__global__ __launch_bounds__(256)
void gemm_out(const short* __restrict__ A, const short* __restrict__ Bw,
              float* __restrict__ C)
{
    __shared__ __align__(16) short As[64*32];
    __shared__ __align__(16) short Bs[128*32];
    const int tid = threadIdx.x;
    const int w = tid >> 6, lane = tid & 63, quad = lane >> 4, l16 = lane & 15;
    const int bm0 = blockIdx.x * 64, bn0 = blockIdx.y * 128;

    const int srow = tid >> 2;
    const int skch = (tid & 3) * 8;
    const short* gA  = A  + (size_t)(bm0 + srow) * 1024 + skch;
    const short* gB0 = Bw + (size_t)(bn0 + srow) * 1024 + skch;
    const short* gB1 = Bw + (size_t)(bn0 + 64 + srow) * 1024 + skch;
    short* lA  = As + w*512;
    short* lB0 = Bs + w*512;
    short* lB1 = Bs + 2048 + w*512;

    f32x4 acc[4][2];
    #pragma unroll
    for (int i = 0; i < 4; ++i) {
        acc[i][0] = (f32x4){0.f,0.f,0.f,0.f};
        acc[i][1] = (f32x4){0.f,0.f,0.f,0.f};
    }

    for (int k0 = 0; k0 < 1024; k0 += 32) {
        __syncthreads();
        gld16(gA  + k0, lA);
        gld16(gB0 + k0, lB0);
        gld16(gB1 + k0, lB1);
        __syncthreads();
        short8 af[4], bfr[2];
        #pragma unroll
        for (int i = 0; i < 4; ++i)
            af[i] = *(const short8*)(As + (i*16 + l16)*32 + quad*8);
        #pragma unroll
        for (int j = 0; j < 2; ++j)
            bfr[j] = *(const short8*)(Bs + (w*32 + j*16 + l16)*32 + quad*8);
        #pragma unroll
        for (int i = 0; i < 4; ++i)
            #pragma unroll
            for (int j = 0; j < 2; ++j)
                acc[i][j] = __builtin_amdgcn_mfma_f32_16x16x32_bf16(af[i], bfr[j], acc[i][j], 0, 0, 0);
    }

    #pragma unroll
    for (int i = 0; i < 4; ++i)
        #pragma unroll
        for (int r = 0; r < 4; ++r) {
            const int m = bm0 + i*16 + quad*4 + r;
            #pragma unroll
            for (int j = 0; j < 2; ++j) {
                const int n = bn0 + w*32 + j*16 + l16;
                C[(size_t)m*1024 + n] = acc[i][j][r];
            }
        }
}

// ---------------- RMSNorm + RoPE, in place on bf16 (q gets 1/8*log2e folded) ----------------
__global__ __launch_bounds__(256)
void rmsnorm_rope(short* __restrict__ qbh, short* __restrict__ kbh,
                  const float* __restrict__ q_scale, const float* __restrict__ k_scale,
                  const float* __restrict__ rope_cos, const float* __restrict__ rope_sin)
{
    const int lane = threadIdx.x & 63;
    const int wid  = threadIdx.x >> 6;
    const int row  = blockIdx.x * 4 + wid;
    const bool isq = (blockIdx.y == 0);
    short* t = isq ? qbh : kbh;
    const float* sc = isq ? q_scale : k_scale;
    const int s = row & (S_-1);
    float v = bf2f(t[(size_t)row * HD_ + lane]);
    float ssum = v * v;
    #pragma unroll
    for (int m = 32; m >= 1; m >>= 1) ssum += __shfl_xor(ssum, m, 64);
    float r = rsqrtf(ssum * (1.0f/64.0f) + 1e-6f);
    float nv = v * r * sc[lane];
    const int p = lane >> 1;
    float c  = rope_cos[s*32 + p];
    float sn = rope_sin[s*32 + p];
    float partner = __shfl_xor(nv, 1, 64);
    float outv = (lane & 1) ? (partner * sn + nv * c) : (nv * c - partner * sn);
    if (isq) outv *= 0.18033688011112042f;   // (1/8) * log2(e)
    t[(size_t)row * HD_ + lane] = f2bf(outv);
}

// ---------------- MFMA flash attention partial, split-K=2, prefetched ----------------
// grid (S/128, B*H, 2), 256 thr (4 waves x 32 q). Fixed-m (12) softmax, log2 domain;
// partials over 1024 keys sum directly. O partial f16 [sp][B,S,H,HD]; l fp32 [sp][B*H,S].
__global__ __launch_bounds__(256, 2)
void flash_mfma(const short* __restrict__ qb, const short* __restrict__ kb,
                const short* __restrict__ vt, short* __restrict__ po, float* __restrict__ pl)
{
    __shared__ __align__(16) short Ks[64*64];
    __shared__ __align__(16) short Vs[64*64];   // f16 bits, [d][key] swizzled

    const int tid  = threadIdx.x;
    const int wv   = tid >> 6;
    const int lane = tid & 63;
    const int quad = lane >> 4;
    const int l16  = lane & 15;
    const int bh   = blockIdx.y;
    const int b    = bh >> 4, h = bh & (H_-1);
    const int q0   = blockIdx.x * 128 + wv * 32;
    const int sp   = blockIdx.z;
    const int kt0  = sp * 1024;
    const size_t hbase = (size_t)bh * S_ * HD_;
    const size_t vbase = (size_t)bh * HD_ * S_;
    short* po_sp = po + (size_t)sp * 4194304;
    float* pl_sp = pl + (size_t)sp * 65536;

    // staging decomposition for this thread's two 16B chunks
    const int c0r = tid >> 3,       c0c = tid & 7;
    const int c1r = (tid+256) >> 3, c1c = (tid+256) & 7;

    short8 qfrag[2][2];
    #pragma unroll
    for (int qf = 0; qf < 2; ++qf)
        #pragma unroll
        for (int c = 0; c < 2; ++c)
            qfrag[qf][c] = *(const short8*)(qb + hbase + (size_t)(q0 + qf*16 + l16)*HD_ + c*32 + quad*8);

    f32x4 Oacc[2][4];
    #pragma unroll
    for (int qf = 0; qf < 2; ++qf)
        #pragma unroll
        for (int dt = 0; dt < 4; ++dt) Oacc[qf][dt] = (f32x4){0.f,0.f,0.f,0.f};
    float l_lane[2] = {0.f, 0.f};

    // prefetch tile 0 into registers
    short8 rk0 = *(const short8*)(kb + hbase + (size_t)(kt0 + c0r)*HD_ + c0c*8);
    short8 rk1 = *(const short8*)(kb + hbase + (size_t)(kt0 + c1r)*HD_ + c1c*8);
    short8 rv0 = *(const short8*)(vt + vbase + (size_t)c0r*S_ + kt0 + c0c*8);
    short8 rv1 = *(const short8*)(vt + vbase + (size_t)c1r*S_ + kt0 + c1c*8);

    #pragma unroll 1
    for (int t = 0; t < 16; ++t) {
        __syncthreads();
        *(short8*)(Ks + c0r*64 + ((c0c ^ (c0r & 7)) << 3)) = rk0;
        *(short8*)(Ks + c1r*64 + ((c1c ^ (c1r & 7)) << 3)) = rk1;
        *(short8*)(Vs + c0r*64 + ((c0c ^ (c0r & 7)) << 3)) = rv0;
        *(short8*)(Vs + c1r*64 + ((c1c ^ (c1r & 7)) << 3)) = rv1;
        __syncthreads();
        if (t < 15) {
            const int ktn = kt0 + (t+1)*64;
            rk0 = *(const short8*)(kb + hbase + (size_t)(ktn + c0r)*HD_ + c0c*8);
            rk1 = *(const short8*)(kb + hbase + (size_t)(ktn + c1r)*HD_ + c1c*8);
            rv0 = *(const short8*)(vt + vbase + (size_t)c0r*S_ + ktn + c0c*8);
            rv1 = *(const short8*)(vt + vbase + (size_t)c1r*S_ + ktn + c1c*8);
        }

        #pragma unroll
        for (int st = 0; st < 4; ++st) {
            short8 kf0 = *(const short8*)(Ks + (st*16 + l16)*64 + (((quad    ) ^ (l16 & 7)) << 3));
            short8 kf1 = *(const short8*)(Ks + (st*16 + l16)*64 + (((4 + quad) ^ (l16 & 7)) << 3));
            #pragma unroll
            for (int qf = 0; qf < 2; ++qf) {
                f32x4 acc = (f32x4){0.f,0.f,0.f,0.f};
                acc = __builtin_amdgcn_mfma_f32_16x16x32_bf16(kf0, qfrag[qf][0], acc, 0, 0, 0);
                acc = __builtin_amdgcn_mfma_f32_16x16x32_bf16(kf1, qfrag[qf][1], acc, 0, 0, 0);
                half4 pb;
                #pragma unroll
                for (int r = 0; r < 4; ++r) {
                    float p = __builtin_amdgcn_exp2f(acc[r] - 12.0f);
                    l_lane[qf] += p;
                    pb[r] = (_Float16)p;
                }
                const int ch16 = st*2 + (quad >> 1);
                const int sw   = ((ch16 ^ (l16 & 7)) << 3) + (quad & 1)*4;
                #pragma unroll
                for (int dt = 0; dt < 4; ++dt) {
                    half4 va = *(const half4*)(Vs + (dt*16 + l16)*64 + sw);
                    Oacc[qf][dt] = __builtin_amdgcn_mfma_f32_16x16x16f16(va, pb, Oacc[qf][dt], 0, 0, 0);
                }
            }
        }
    }

    // l partial: reduce across quads; lanes quad==0 store
    #pragma unroll
    for (int qf = 0; qf < 2; ++qf) {
        l_lane[qf] += __shfl_xor(l_lane[qf], 16, 64);
        l_lane[qf] += __shfl_xor(l_lane[qf], 32, 64);
        if (quad == 0) pl_sp[(size_t)bh*S_ + q0 + qf*16 + l16] = l_lane[qf];
    }
    // O partial f16, unnormalized: [B,S,H,HD]
    #pragma unroll
    for (int qf = 0; qf < 2; ++qf) {
        const int s = q0 + qf*16 + l16;
        #pragma unroll
        for (int dt = 0; dt < 4; ++dt) {
            short4v o;
            #pragma unroll
            for (int r = 0; r < 4; ++r) o[r] = f2h(Oacc[qf][dt][r]);
            *(short4v*)(po_sp + (((size_t)b*S_ + s)*H_ + h)*HD_ + dt*16 + quad*4) = o;
        }
    }
}

// ---------------- combine split-K partials -> attn bf16 [B,S,H*HD] ----------------
__global__ __launch_bounds__(256)
void flash_combine(const short* __restrict__ po, const float* __restrict__ pl,
                   short* __restrict__ attnb)
{
    const size_t idx4 = ((size_t)blockIdx.x * 256 + threadIdx.x) * 4;
    const size_t row  = idx4 >> 6;            // (b*S+s)*H + h
    const int h  = (int)(row & 15);
    const size_t bs = row >> 4;
    const int b  = (int)(bs >> 11);
    const int s  = (int)(bs & (S_-1));
    const int bh = b*16 + h;
    const float l = pl[(size_t)bh*S_ + s] + pl[65536 + (size_t)bh*S_ + s];
    const float inv = 1.0f / l;
    short4v a0 = *(const short4v*)(po + idx4);
    short4v a1 = *(const short4v*)(po + 4194304 + idx4);
    short4v o;
    #pragma unroll
    for (int i = 0; i < 4; ++i) o[i] = f2bf((h2f(a0[i]) + h2f(a1[i])) * inv);
    *(short4v*)(attnb + idx4) = o;
}

extern "C" void kernel_launch(void* const* d_in, const int* in_sizes, int n_in,
                              void* d_out, int out_size, void* d_ws, size_t ws_size,
                              hipStream_t stream)
{
    (void)in_sizes; (void)n_in; (void)out_size; (void)ws_size;
    const float* x        = (const float*)d_in[0];
    const float* wq       = (const float*)d_in[1];
    const float* wk       = (const float*)d_in[2];
    const float* wv       = (const float*)d_in[3];
    const float* wo       = (const float*)d_in[4];
    const float* q_scale  = (const float*)d_in[5];
    const float* k_scale  = (const float*)d_in[6];
    const float* rope_cos = (const float*)d_in[7];
    const float* rope_sin = (const float*)d_in[8];
    float* out = (float*)d_out;
    short* ws  = (short*)d_ws;

    short* qbh   = ws;                 // 4M shorts
    short* kbh   = ws + 4194304;
    short* vt    = ws + 8388608;
    short* attnb = ws + 12582912;
    short* xb    = ws + 16777216;
    short* wqkvb = ws + 20971520;      // 3M shorts
    short* wob   = ws + 24117248;      // 1M shorts
    short* po    = ws + 25165824;      // 2 x 4M shorts (f16)
    float* pl    = (float*)(ws + 33554432);  // 2 x 64K floats

    convert_bf16<<<dim3(8192), 256, 0, stream>>>(x, wq, wk, wv, wo, xb, wqkvb, wob);
    gemm_qkv<<<dim3(M_/128, 24), 256, 0, stream>>>(xb, wqkvb, qbh, kbh, vt);
    rmsnorm_rope<<<dim3(B_*H_*S_/4, 2), 256, 0, stream>>>(qbh, kbh, q_scale, k_scale, rope_cos, rope_sin);
    flash_mfma<<<dim3(S_/128, B_*H_, 2), 256, 0, stream>>>(qbh, kbh, vt, po, pl);
    flash_combine<<<dim3(4096), 256, 0, stream>>>(po, pl, attnb);
    gemm_out<<<dim3(M_/64, D_/128), 256, 0, stream>>>(attnb, wob, out);
}

// Round 6
// 222.566 us; speedup vs baseline: 6.5314x; 1.0141x over previous
//
#include <hip/hip_runtime.h>
#include <hip/hip_bf16.h>

// RoPEAttention B=2 S=2048 D=1024 H=16 HD=64, fp32 in/out.
// R6: flash V-frag hoist (query-independent LDS reads out of qf loop);
//     combine fused into gemm_out A-staging (kernel + attnb round-trip removed).
// ws (shorts): qbh[0,4M) kbh[4M,8M) vt[8M,12M) (attnb slot unused) xb[16M,20M)
//              wqkvb[20M,23M) wob[23M,24M) po[24M,32M) pl(fp32)[32M shorts...)

#define B_ 2
#define S_ 2048
#define D_ 1024
#define H_ 16
#define HD_ 64
#define M_ (B_*S_)

typedef __attribute__((ext_vector_type(8))) short short8;
typedef __attribute__((ext_vector_type(4))) short short4v;
typedef __attribute__((ext_vector_type(4))) float f32x4;
typedef __attribute__((ext_vector_type(4))) _Float16 half4;
typedef __attribute__((ext_vector_type(8))) _Float16 half8;

static __device__ __forceinline__ short f2bf(float f) {
    __hip_bfloat16 h = __float2bfloat16(f);
    return *reinterpret_cast<short*>(&h);
}
static __device__ __forceinline__ short f2h(float f) {
    _Float16 h = (_Float16)f;
    return *reinterpret_cast<short*>(&h);
}
static __device__ __forceinline__ float bf2f(short s) {
    unsigned u = ((unsigned)(unsigned short)s) << 16;
    float f; __builtin_memcpy(&f, &u, 4); return f;
}

typedef __attribute__((address_space(1))) const unsigned int gu32_t;
typedef __attribute__((address_space(3))) unsigned int lu32_t;
static __device__ __forceinline__ void gld16(const short* g, short* l) {
    __builtin_amdgcn_global_load_lds((gu32_t*)g, (lu32_t*)l, 16, 0, 0);
}

// ---------------- fp32 -> bf16 convert: x, wq|wk|wv (concat), wo ----------------
__global__ __launch_bounds__(256)
void convert_bf16(const float* __restrict__ x,
                  const float* __restrict__ wq, const float* __restrict__ wk,
                  const float* __restrict__ wv, const float* __restrict__ wo,
                  short* __restrict__ xb, short* __restrict__ wqkvb, short* __restrict__ wob)
{
    const size_t t4 = ((size_t)blockIdx.x * 256 + threadIdx.x) * 4;
    const float* src; short* dst; size_t off, doff;
    if (t4 < 4194304)      { src = x;  dst = xb;    off = t4;           doff = t4; }
    else if (t4 < 5242880) { src = wq; dst = wqkvb; off = t4 - 4194304; doff = t4 - 4194304; }
    else if (t4 < 6291456) { src = wk; dst = wqkvb; off = t4 - 5242880; doff = t4 - 4194304; }
    else if (t4 < 7340032) { src = wv; dst = wqkvb; off = t4 - 6291456; doff = t4 - 4194304; }
    else                   { src = wo; dst = wob;   off = t4 - 7340032; doff = t4 - 7340032; }
    float4 v = *(const float4*)(src + off);
    short4v s = { f2bf(v.x), f2bf(v.y), f2bf(v.z), f2bf(v.w) };
    *(short4v*)(dst + doff) = s;
}

// ---------------- bf16 MFMA GEMM NT 128x128 (qkv fused, N=3072) ----------------
// n>>10==0 -> Qb bf16 [B,H,S,HD]; ==1 -> Kb bf16; ==2 -> Vt f16 [B,H,HD,S]
__global__ __launch_bounds__(256)
void gemm_qkv(const short* __restrict__ A, const short* __restrict__ Bw,
              short* __restrict__ Qb, short* __restrict__ Kb, short* __restrict__ Vt)
{
    __shared__ __align__(16) short As[128*32];
    __shared__ __align__(16) short Bs[128*32];
    const int tid = threadIdx.x;
    const int w = tid >> 6, lane = tid & 63, quad = lane >> 4, l16 = lane & 15;
    const int wr = w >> 1, wc = w & 1;
    const int bm0 = blockIdx.x * 128, bn0 = blockIdx.y * 128;

    const int srow = tid >> 2;
    const int skch = (tid & 3) * 8;
    const short* gA0 = A  + (size_t)(bm0 + srow) * 1024 + skch;
    const short* gA1 = A  + (size_t)(bm0 + 64 + srow) * 1024 + skch;
    const short* gB0 = Bw + (size_t)(bn0 + srow) * 1024 + skch;
    const short* gB1 = Bw + (size_t)(bn0 + 64 + srow) * 1024 + skch;
    short* lA0 = As + w*512;
    short* lA1 = As + 2048 + w*512;
    short* lB0 = Bs + w*512;
    short* lB1 = Bs + 2048 + w*512;

    f32x4 acc[4][4];
    #pragma unroll
    for (int i = 0; i < 4; ++i)
        #pragma unroll
        for (int j = 0; j < 4; ++j) acc[i][j] = (f32x4){0.f,0.f,0.f,0.f};

    for (int k0 = 0; k0 < 1024; k0 += 32) {
        __syncthreads();
        gld16(gA0 + k0, lA0);
        gld16(gA1 + k0, lA1);
        gld16(gB0 + k0, lB0);
        gld16(gB1 + k0, lB1);
        __syncthreads();
        short8 af[4], bfr[4];
        #pragma unroll
        for (int i = 0; i < 4; ++i)
            af[i] = *(const short8*)(As + (wr*64 + i*16 + l16)*32 + quad*8);
        #pragma unroll
        for (int j = 0; j < 4; ++j)
            bfr[j] = *(const short8*)(Bs + (wc*64 + j*16 + l16)*32 + quad*8);
        #pragma unroll
        for (int i = 0; i < 4; ++i)
            #pragma unroll
            for (int j = 0; j < 4; ++j)
                acc[i][j] = __builtin_amdgcn_mfma_f32_16x16x32_bf16(af[i], bfr[j], acc[i][j], 0, 0, 0);
    }

    #pragma unroll
    for (int i = 0; i < 4; ++i) {
        #pragma unroll
        for (int r = 0; r < 4; ++r) {
            const int m = bm0 + wr*64 + i*16 + quad*4 + r;
            #pragma unroll
            for (int j = 0; j < 4; ++j) {
                const int n = bn0 + wc*64 + j*16 + l16;
                const float v = acc[i][j][r];
                const int which = n >> 10, nn = n & 1023;
                const int h = nn >> 6, hd = nn & 63;
                const int b = m >> 11, s = m & (S_-1);
                if (which == 0)      Qb[(((size_t)b*H_ + h)*S_ + s)*HD_ + hd] = f2bf(v);
                else if (which == 1) Kb[(((size_t)b*H_ + h)*S_ + s)*HD_ + hd] = f2bf(v);
                else                 Vt[(((size_t)b*H_ + h)*HD_ + hd)*S_ + s] = f2h(v);
            }
        }
    }
}

// ---------------- out-proj GEMM 64x128, split-K combine fused into A-staging ----------------
// A[m,k] = (po0[m,k] + po1[m,k]) / (l0[m,h(k)] + l1[m,h(k)]), cvt bf16 on the fly.
__global__ __launch_bounds__(256)
void gemm_out(const short* __restrict__ po, const float* __restrict__ pl,
              const short* __restrict__ Bw, float* __restrict__ C)
{
    __shared__ __align__(16) short As[64*32];
    __shared__ __align__(16) short Bs[128*32];
    const int tid = threadIdx.x;
    const int w = tid >> 6, lane = tid & 63, quad = lane >> 4, l16 = lane & 15;
    const int bm0 = blockIdx.x * 64, bn0 = blockIdx.y * 128;

    const int srow = tid >> 2;
    const int skch = (tid & 3) * 8;
    const int m = bm0 + srow;
    const int b = m >> 11, s = m & (S_-1);
    const short* gB0 = Bw + (size_t)(bn0 + srow) * 1024 + skch;
    const short* gB1 = Bw + (size_t)(bn0 + 64 + srow) * 1024 + skch;
    short* lB0 = Bs + w*512;
    short* lB1 = Bs + 2048 + w*512;

    // per-head inverse denominators for this thread's A-row
    float inv[16];
    #pragma unroll
    for (int h = 0; h < 16; ++h)
        inv[h] = 1.0f / (pl[((size_t)(b*16 + h))*S_ + s] + pl[65536 + ((size_t)(b*16 + h))*S_ + s]);

    f32x4 acc[4][2];
    #pragma unroll
    for (int i = 0; i < 4; ++i) {
        acc[i][0] = (f32x4){0.f,0.f,0.f,0.f};
        acc[i][1] = (f32x4){0.f,0.f,0.f,0.f};
    }

    for (int k0 = 0; k0 < 1024; k0 += 32) {
        const int h = k0 >> 6;      // skch+7 <= 31 so head is uniform per iter
        half8 p0 = *(const half8*)(po +            (size_t)m*1024 + k0 + skch);
        half8 p1 = *(const half8*)(po + 4194304 + (size_t)m*1024 + k0 + skch);
        short8 a;
        #pragma unroll
        for (int j = 0; j < 8; ++j)
            a[j] = f2bf(((float)p0[j] + (float)p1[j]) * inv[h]);
        __syncthreads();
        *(short8*)(As + srow*32 + skch) = a;
        gld16(gB0 + k0, lB0);
        gld16(gB1 + k0, lB1);
        __syncthreads();
        short8 af[4], bfr[2];
        #pragma unroll
        for (int i = 0; i < 4; ++i)
            af[i] = *(const short8*)(As + (i*16 + l16)*32 + quad*8);
        #pragma unroll
        for (int j = 0; j < 2; ++j)
            bfr[j] = *(const short8*)(Bs + (w*32 + j*16 + l16)*32 + quad*8);
        #pragma unroll
        for (int i = 0; i < 4; ++i)
            #pragma unroll
            for (int j = 0; j < 2; ++j)
                acc[i][j] = __builtin_amdgcn_mfma_f32_16x16x32_bf16(af[i], bfr[j], acc[i][j], 0, 0, 0);
    }

    #pragma unroll
    for (int i = 0; i < 4; ++i)
        #pragma unroll
        for (int r = 0; r < 4; ++r) {
            const int mm = bm0 + i*16 + quad*4 + r;
            #pragma unroll
            for (int j = 0; j < 2; ++j) {
                const int n = bn0 + w*32 + j*16 + l16;
                C[(size_t)mm*1024 + n] = acc[i][j][r];
            }
        }
}

// ---------------- RMSNorm + RoPE, in place on bf16 (q gets 1/8*log2e folded) ----------------
__global__ __launch_bounds__(256)
void rmsnorm_rope(short* __restrict__ qbh, short* __restrict__ kbh,
                  const float* __restrict__ q_scale, const float* __restrict__ k_scale,
                  const float* __restrict__ rope_cos, const float* __restrict__ rope_sin)
{
    const int lane = threadIdx.x & 63;
    const int wid  = threadIdx.x >> 6;
    const int row  = blockIdx.x * 4 + wid;
    const bool isq = (blockIdx.y == 0);
    short* t = isq ? qbh : kbh;
    const float* sc = isq ? q_scale : k_scale;
    const int s = row & (S_-1);
    float v = bf2f(t[(size_t)row * HD_ + lane]);
    float ssum = v * v;
    #pragma unroll
    for (int m = 32; m >= 1; m >>= 1) ssum += __shfl_xor(ssum, m, 64);
    float r = rsqrtf(ssum * (1.0f/64.0f) + 1e-6f);
    float nv = v * r * sc[lane];
    const int p = lane >> 1;
    float c  = rope_cos[s*32 + p];
    float sn = rope_sin[s*32 + p];
    float partner = __shfl_xor(nv, 1, 64);
    float outv = (lane & 1) ? (partner * sn + nv * c) : (nv * c - partner * sn);
    if (isq) outv *= 0.18033688011112042f;   // (1/8) * log2(e)
    t[(size_t)row * HD_ + lane] = f2bf(outv);
}

// ---------------- MFMA flash attention partial, split-K=2, prefetched ----------------
// grid (S/128, B*H, 2), 256 thr (4 waves x 32 q). Fixed-m (12) softmax, log2 domain;
// partials over 1024 keys sum directly. O partial f16 [sp][B,S,H,HD]; l fp32 [sp][B*H,S].
__global__ __launch_bounds__(256, 2)
void flash_mfma(const short* __restrict__ qb, const short* __restrict__ kb,
                const short* __restrict__ vt, short* __restrict__ po, float* __restrict__ pl)
{
    __shared__ __align__(16) short Ks[64*64];
    __shared__ __align__(16) short Vs[64*64];   // f16 bits, [d][key] swizzled

    const int tid  = threadIdx.x;
    const int wv   = tid >> 6;
    const int lane = tid & 63;
    const int quad = lane >> 4;
    const int l16  = lane & 15;
    const int bh   = blockIdx.y;
    const int b    = bh >> 4, h = bh & (H_-1);
    const int q0   = blockIdx.x * 128 + wv * 32;
    const int sp   = blockIdx.z;
    const int kt0  = sp * 1024;
    const size_t hbase = (size_t)bh * S_ * HD_;
    const size_t vbase = (size_t)bh * HD_ * S_;
    short* po_sp = po + (size_t)sp * 4194304;
    float* pl_sp = pl + (size_t)sp * 65536;

    const int c0r = tid >> 3,       c0c = tid & 7;
    const int c1r = (tid+256) >> 3, c1c = (tid+256) & 7;

    short8 qfrag[2][2];
    #pragma unroll
    for (int qf = 0; qf < 2; ++qf)
        #pragma unroll
        for (int c = 0; c < 2; ++c)
            qfrag[qf][c] = *(const short8*)(qb + hbase + (size_t)(q0 + qf*16 + l16)*HD_ + c*32 + quad*8);

    f32x4 Oacc[2][4];
    #pragma unroll
    for (int qf = 0; qf < 2; ++qf)
        #pragma unroll
        for (int dt = 0; dt < 4; ++dt) Oacc[qf][dt] = (f32x4){0.f,0.f,0.f,0.f};
    float l_lane[2] = {0.f, 0.f};

    short8 rk0 = *(const short8*)(kb + hbase + (size_t)(kt0 + c0r)*HD_ + c0c*8);
    short8 rk1 = *(const short8*)(kb + hbase + (size_t)(kt0 + c1r)*HD_ + c1c*8);
    short8 rv0 = *(const short8*)(vt + vbase + (size_t)c0r*S_ + kt0 + c0c*8);
    short8 rv1 = *(const short8*)(vt + vbase + (size_t)c1r*S_ + kt0 + c1c*8);

    #pragma unroll 1
    for (int t = 0; t < 16; ++t) {
        __syncthreads();
        *(short8*)(Ks + c0r*64 + ((c0c ^ (c0r & 7)) << 3)) = rk0;
        *(short8*)(Ks + c1r*64 + ((c1c ^ (c1r & 7)) << 3)) = rk1;
        *(short8*)(Vs + c0r*64 + ((c0c ^ (c0r & 7)) << 3)) = rv0;
        *(short8*)(Vs + c1r*64 + ((c1c ^ (c1r & 7)) << 3)) = rv1;
        __syncthreads();
        if (t < 15) {
            const int ktn = kt0 + (t+1)*64;
            rk0 = *(const short8*)(kb + hbase + (size_t)(ktn + c0r)*HD_ + c0c*8);
            rk1 = *(const short8*)(kb + hbase + (size_t)(ktn + c1r)*HD_ + c1c*8);
            rv0 = *(const short8*)(vt + vbase + (size_t)c0r*S_ + ktn + c0c*8);
            rv1 = *(const short8*)(vt + vbase + (size_t)c1r*S_ + ktn + c1c*8);
        }

        #pragma unroll
        for (int st = 0; st < 4; ++st) {
            short8 kf0 = *(const short8*)(Ks + (st*16 + l16)*64 + (((quad    ) ^ (l16 & 7)) << 3));
            short8 kf1 = *(const short8*)(Ks + (st*16 + l16)*64 + (((4 + quad) ^ (l16 & 7)) << 3));
            // V fragments are query-independent: load once per st, reuse for both qf
            const int ch16 = st*2 + (quad >> 1);
            const int sw   = ((ch16 ^ (l16 & 7)) << 3) + (quad & 1)*4;
            half4 va[4];
            #pragma unroll
            for (int dt = 0; dt < 4; ++dt)
                va[dt] = *(const half4*)(Vs + (dt*16 + l16)*64 + sw);
            #pragma unroll
            for (int qf = 0; qf < 2; ++qf) {
                f32x4 acc = (f32x4){0.f,0.f,0.f,0.f};
                acc = __builtin_amdgcn_mfma_f32_16x16x32_bf16(kf0, qfrag[qf][0], acc, 0, 0, 0);
                acc = __builtin_amdgcn_mfma_f32_16x16x32_bf16(kf1, qfrag[qf][1], acc, 0, 0, 0);
                half4 pb;
                #pragma unroll
                for (int r = 0; r < 4; ++r) {
                    float p = __builtin_amdgcn_exp2f(acc[r] - 12.0f);
                    l_lane[qf] += p;
                    pb[r] = (_Float16)p;
                }
                #pragma unroll
                for (int dt = 0; dt < 4; ++dt)
                    Oacc[qf][dt] = __builtin_amdgcn_mfma_f32_16x16x16f16(va[dt], pb, Oacc[qf][dt], 0, 0, 0);
            }
        }
    }

    #pragma unroll
    for (int qf = 0; qf < 2; ++qf) {
        l_lane[qf] += __shfl_xor(l_lane[qf], 16, 64);
        l_lane[qf] += __shfl_xor(l_lane[qf], 32, 64);
        if (quad == 0) pl_sp[(size_t)bh*S_ + q0 + qf*16 + l16] = l_lane[qf];
    }
    #pragma unroll
    for (int qf = 0; qf < 2; ++qf) {
        const int s = q0 + qf*16 + l16;
        #pragma unroll
        for (int dt = 0; dt < 4; ++dt) {
            short4v o;
            #pragma unroll
            for (int r = 0; r < 4; ++r) o[r] = f2h(Oacc[qf][dt][r]);
            *(short4v*)(po_sp + (((size_t)b*S_ + s)*H_ + h)*HD_ + dt*16 + quad*4) = o;
        }
    }
}

extern "C" void kernel_launch(void* const* d_in, const int* in_sizes, int n_in,
                              void* d_out, int out_size, void* d_ws, size_t ws_size,
                              hipStream_t stream)
{
    (void)in_sizes; (void)n_in; (void)out_size; (void)ws_size;
    const float* x        = (const float*)d_in[0];
    const float* wq       = (const float*)d_in[1];
    const float* wk       = (const float*)d_in[2];
    const float* wv       = (const float*)d_in[3];
    const float* wo       = (const float*)d_in[4];
    const float* q_scale  = (const float*)d_in[5];
    const float* k_scale  = (const float*)d_in[6];
    const float* rope_cos = (const float*)d_in[7];
    const float* rope_sin = (const float*)d_in[8];
    float* out = (float*)d_out;
    short* ws  = (short*)d_ws;

    short* qbh   = ws;                 // 4M shorts
    short* kbh   = ws + 4194304;
    short* vt    = ws + 8388608;
    short* xb    = ws + 16777216;
    short* wqkvb = ws + 20971520;      // 3M shorts
    short* wob   = ws + 24117248;      // 1M shorts
    short* po    = ws + 25165824;      // 2 x 4M shorts (f16)
    float* pl    = (float*)(ws + 33554432);  // 2 x 64K floats

    convert_bf16<<<dim3(8192), 256, 0, stream>>>(x, wq, wk, wv, wo, xb, wqkvb, wob);
    gemm_qkv<<<dim3(M_/128, 24), 256, 0, stream>>>(xb, wqkvb, qbh, kbh, vt);
    rmsnorm_rope<<<dim3(B_*H_*S_/4, 2), 256, 0, stream>>>(qbh, kbh, q_scale, k_scale, rope_cos, rope_sin);
    flash_mfma<<<dim3(S_/128, B_*H_, 2), 256, 0, stream>>>(qbh, kbh, vt, po, pl);
    gemm_out<<<dim3(M_/64, D_/128), 256, 0, stream>>>(po, pl, wob, out);
}